// Round 14
// baseline (400.829 us; speedup 1.0000x reference)
//
#include <hip/hip_runtime.h>

#define BB 16384
#define SS 200
#define NF 6
#define HH 50
#define TT 5
#define ROWS 64          // per block: 4 waves x 16 rows
#define BLK 256
#define SEQ_STRIDE (SS * NF)   // 1200
#define NT 13            // M-tiles (200 gate-rows -> 13 x 16, tail phantom)

typedef _Float16 half8 __attribute__((ext_vector_type(8)));
typedef __attribute__((ext_vector_type(4))) float f32x4;

#define LOG2E 1.44269504088896f

__device__ __forceinline__ unsigned short h_bits(_Float16 h) {
    return __builtin_bit_cast(unsigned short, h);
}
__device__ __forceinline__ float h_f(unsigned short b) {
    return (float)__builtin_bit_cast(_Float16, b);
}

// A fragment for 8 consecutive k of one gate-row, pre-scaled; k==56 carries the
// fused bias (B[56][*] is fixed at 1.0, so bias arrives through the MFMA).
__device__ __forceinline__ half8 mk8(const float* __restrict__ Wih,
                                     const float* __restrict__ Whh,
                                     const float* __restrict__ bih,
                                     const float* __restrict__ bhh,
                                     bool valid, int orow, float sc, int kbase)
{
    half8 r;
    #pragma unroll
    for (int j = 0; j < 8; ++j) {
        int k = kbase + j;
        float v = 0.0f;
        if (valid) {
            if (k < NF)            v = Wih[orow * NF + k];
            else if (k < NF + HH)  v = Whh[orow * HH + (k - NF)];
            else if (k == NF + HH) v = bih[orow] + bhh[orow];
        }
        r[j] = (_Float16)(v * sc);
    }
    return r;
}

// acc is directly the exp2 argument (weights/bias pre-scaled).
__device__ __forceinline__ void cell_upd(const f32x4& g, float& c, bool real,
                                         int posQ, unsigned short* B)
{
    float si = __builtin_amdgcn_rcpf(1.0f + __builtin_amdgcn_exp2f(g[0]));
    float sf = __builtin_amdgcn_rcpf(1.0f + __builtin_amdgcn_exp2f(g[1]));
    float tg = fmaf(2.0f, __builtin_amdgcn_rcpf(1.0f + __builtin_amdgcn_exp2f(g[2])), -1.0f);
    float so = __builtin_amdgcn_rcpf(1.0f + __builtin_amdgcn_exp2f(g[3]));
    float cc = sf * c + si * tg;
    c = cc;
    float tc = fmaf(2.0f, __builtin_amdgcn_rcpf(1.0f +
                    __builtin_amdgcn_exp2f(-2.0f * LOG2E * cc)), -1.0f);
    float hh = so * tc;
    if (real) B[posQ] = h_bits((_Float16)hh);
}

__global__ __launch_bounds__(BLK, 1) void lstm_wave(
    const float* __restrict__ seq,
    const float* __restrict__ Wih_e, const float* __restrict__ Whh_e,
    const float* __restrict__ bih_e, const float* __restrict__ bhh_e,
    const float* __restrict__ Wih_d, const float* __restrict__ Whh_d,
    const float* __restrict__ bih_d, const float* __restrict__ bhh_d,
    const float* __restrict__ Wl, const float* __restrict__ bl,
    float* __restrict__ out)
{
    __shared__ half8 Bsh8[512];             // 4 waves x 128 chunks (2KB each)
    __shared__ float xs[ROWS * 97];         // 16 steps x 6 feats per row
    __shared__ float Wls[NF * HH];
    __shared__ float bls[NF];

    const int tid  = threadIdx.x;
    const int w    = tid >> 6;              // 4 waves, each fully autonomous
    const int lane = tid & 63;
    const int q    = lane >> 4;
    const int l15  = lane & 15;
    const int b0   = blockIdx.x * ROWS;
    const int rw   = w * 16 + l15;          // wave-local row -> block row

    half8*          B8 = Bsh8 + w * 128;    // this wave's B state (single buffer)
    unsigned short* B  = (unsigned short*)B8;

    // ---- one-time init ----
    for (int i = tid; i < 512; i += BLK) Bsh8[i] = (half8)(_Float16)0.0f;
    for (int i = tid; i < NF * HH; i += BLK) Wls[i] = Wl[i];
    if (tid < NF) bls[tid] = bl[tid];
    for (int idx = tid; idx < ROWS * 96; idx += BLK) {
        int row = idx / 96, cc = idx - row * 96;
        xs[row * 97 + cc] = seq[(size_t)(b0 + row) * SEQ_STRIDE + cc];
    }
    __syncthreads();

    // k=56 "bias lane" of B = 1.0 (chunk 112+row, elem 0)
    if (lane < 16) B[(112 + lane) * 8] = h_bits((_Float16)1.0f);
    // x_0 into B slots k=0..5 (pos = row*8 + n)
    B[l15 * 8 + q] = h_bits((_Float16)xs[rw * 97 + q]);
    if (lane < 32) B[l15 * 8 + 4 + q] = h_bits((_Float16)xs[rw * 97 + 4 + q]);

    // ---- A fragments (all 13 tiles) in registers; hpos precomputed ----
    half8 a0[NT], a1[NT];
    float cst[NT];
    int   hpos[NT];
    bool  realu[NT];
    #pragma unroll
    for (int i = 0; i < NT; ++i) {
        int g2 = i * 16 + l15, u = g2 >> 2, gt = g2 & 3;
        bool v = (u < HH);
        int orow = gt * HH + u;
        float sc = (gt == 2) ? -2.0f * LOG2E : -LOG2E;
        a0[i] = mk8(Wih_e, Whh_e, bih_e, bhh_e, v, orow, sc, q * 8);
        a1[i] = mk8(Wih_e, Whh_e, bih_e, bhh_e, v, orow, sc, 32 + q * 8);
        cst[i] = 0.0f;
        int uu = i * 4 + q, k = NF + uu;
        hpos[i] = (((k >> 5) * 64) + ((k >> 3) & 3) * 16 + l15) * 8 + (k & 7);
        realu[i] = (uu < HH);
    }

    // ==== encoder: 200 steps, no per-step barriers ====
    for (int t = 0; t < SS; ++t) {
        half8 bh0 = B8[lane];
        half8 bh1 = B8[64 + lane];
        f32x4 acc[NT];
        #pragma unroll
        for (int i = 0; i < NT; ++i) {
            acc[i] = (f32x4){0.f, 0.f, 0.f, 0.f};
            acc[i] = __builtin_amdgcn_mfma_f32_16x16x32_f16(a0[i], bh0, acc[i], 0, 0, 0);
        }
        #pragma unroll
        for (int i = 0; i < NT; ++i)
            acc[i] = __builtin_amdgcn_mfma_f32_16x16x32_f16(a1[i], bh1, acc[i], 0, 0, 0);

        if ((t & 15) == 15 && t < 192) {
            // cooperative xs refresh for steps t+1 .. t+16
            __syncthreads();               // all waves done reading old chunk
            const int tn = t + 1;
            for (int idx = tid; idx < ROWS * 96; idx += BLK) {
                int row = idx / 96, cc = idx - row * 96;
                float v = 0.0f;
                if (tn + cc / 6 < SS)
                    v = seq[(size_t)(b0 + row) * SEQ_STRIDE + tn * NF + cc];
                xs[row * 97 + cc] = v;
            }
            __syncthreads();               // new chunk visible
        }

        // x_{t+1} into B (t==199 writes dec_in = x_199, slot 7)
        const int slot = (t < SS - 1) ? ((t + 1) & 15) : 7;
        B[l15 * 8 + q] = h_bits((_Float16)xs[rw * 97 + slot * NF + q]);
        if (lane < 32)
            B[l15 * 8 + 4 + q] = h_bits((_Float16)xs[rw * 97 + slot * NF + 4 + q]);

        #pragma unroll
        for (int i = 0; i < NT; ++i)
            cell_upd(acc[i], cst[i], realu[i], hpos[i], B);
    }

    // ==== switch to decoder weights (registers only, no barrier) ====
    #pragma unroll
    for (int i = 0; i < NT; ++i) {
        int g2 = i * 16 + l15, u = g2 >> 2, gt = g2 & 3;
        bool v = (u < HH);
        int orow = gt * HH + u;
        float sc = (gt == 2) ? -2.0f * LOG2E : -LOG2E;
        a0[i] = mk8(Wih_d, Whh_d, bih_d, bhh_d, v, orow, sc, q * 8);
        a1[i] = mk8(Wih_d, Whh_d, bih_d, bhh_d, v, orow, sc, 32 + q * 8);
    }

    // ==== decoder: 5 steps ====
    for (int k = 0; k < TT; ++k) {
        half8 bh0 = B8[lane];
        half8 bh1 = B8[64 + lane];
        f32x4 acc[NT];
        #pragma unroll
        for (int i = 0; i < NT; ++i) {
            acc[i] = (f32x4){0.f, 0.f, 0.f, 0.f};
            acc[i] = __builtin_amdgcn_mfma_f32_16x16x32_f16(a0[i], bh0, acc[i], 0, 0, 0);
        }
        #pragma unroll
        for (int i = 0; i < NT; ++i)
            acc[i] = __builtin_amdgcn_mfma_f32_16x16x32_f16(a1[i], bh1, acc[i], 0, 0, 0);
        #pragma unroll
        for (int i = 0; i < NT; ++i)
            cell_upd(acc[i], cst[i], realu[i], hpos[i], B);

        // pred = h @ Wl^T + bl  (h read back from B; same-wave DS order)
        float p1 = bls[q];
        float p2 = (lane < 32) ? bls[4 + q] : 0.0f;
        #pragma unroll
        for (int u2 = 0; u2 < HH; ++u2) {
            int kk = NF + u2;
            int pos = ((kk >> 5) * 64 + ((kk >> 3) & 3) * 16 + l15) * 8 + (kk & 7);
            float hv = h_f(B[pos]);
            p1 = fmaf(Wls[q * HH + u2], hv, p1);
            if (lane < 32) p2 = fmaf(Wls[(4 + q) * HH + u2], hv, p2);
        }
        out[(size_t)(b0 + rw) * (TT * NF) + k * NF + q] = p1;
        if (lane < 32)
            out[(size_t)(b0 + rw) * (TT * NF) + k * NF + 4 + q] = p2;

        // feed pred back as next x
        B[l15 * 8 + q] = h_bits((_Float16)p1);
        if (lane < 32) B[l15 * 8 + 4 + q] = h_bits((_Float16)p2);
    }
}

extern "C" void kernel_launch(void* const* d_in, const int* in_sizes, int n_in,
                              void* d_out, int out_size, void* d_ws, size_t ws_size,
                              hipStream_t stream)
{
    const float* seq   = (const float*)d_in[0];
    const float* Wih_e = (const float*)d_in[1];
    const float* Whh_e = (const float*)d_in[2];
    const float* bih_e = (const float*)d_in[3];
    const float* bhh_e = (const float*)d_in[4];
    const float* Wih_d = (const float*)d_in[5];
    const float* Whh_d = (const float*)d_in[6];
    const float* bih_d = (const float*)d_in[7];
    const float* bhh_d = (const float*)d_in[8];
    const float* Wl    = (const float*)d_in[9];
    const float* bl    = (const float*)d_in[10];
    float* out = (float*)d_out;

    dim3 grid(BB / ROWS);   // 256 blocks -> 1 per CU; 4 waves = 1 per SIMD
    dim3 block(BLK);
    lstm_wave<<<grid, block, 0, stream>>>(seq, Wih_e, Whh_e, bih_e, bhh_e,
                                          Wih_d, Whh_d, bih_d, bhh_d,
                                          Wl, bl, out);
}

// Round 15
// 292.599 us; speedup vs baseline: 1.3699x; 1.3699x over previous
//
#include <hip/hip_runtime.h>

#define BB 16384
#define SS 200
#define NF 6
#define HH 50
#define TT 5
#define ROWS 16
#define BLK 128
#define SEQ_STRIDE (SS * NF)   // 1200
#define NTM 7                  // max tiles per wave (wave0: 7, wave1: 6)

typedef _Float16 half8 __attribute__((ext_vector_type(8)));
typedef __attribute__((ext_vector_type(4))) float f32x4;

#define LOG2E 1.44269504088896f

__device__ __forceinline__ unsigned short h_bits(_Float16 h) {
    return __builtin_bit_cast(unsigned short, h);
}
__device__ __forceinline__ float h_f(unsigned short b) {
    return (float)__builtin_bit_cast(_Float16, b);
}

// A fragment for 8 consecutive k of one gate-row, pre-scaled; k==56 carries the
// fused bias (B[56][*] fixed at 1.0 -> bias arrives through the MFMA).
__device__ __forceinline__ half8 mk8(const float* __restrict__ Wih,
                                     const float* __restrict__ Whh,
                                     const float* __restrict__ bih,
                                     const float* __restrict__ bhh,
                                     bool valid, int orow, float sc, int kbase)
{
    half8 r;
    #pragma unroll
    for (int j = 0; j < 8; ++j) {
        int k = kbase + j;
        float v = 0.0f;
        if (valid) {
            if (k < NF)            v = Wih[orow * NF + k];
            else if (k < NF + HH)  v = Whh[orow * HH + (k - NF)];
            else if (k == NF + HH) v = bih[orow] + bhh[orow];
        }
        r[j] = (_Float16)(v * sc);
    }
    return r;
}

// acc is directly the exp2 argument (weights/bias pre-scaled).
__device__ __forceinline__ void cell_upd(const f32x4& g, float& c, bool real,
                                         int posQ, unsigned short* BQ)
{
    float si = __builtin_amdgcn_rcpf(1.0f + __builtin_amdgcn_exp2f(g[0]));
    float sf = __builtin_amdgcn_rcpf(1.0f + __builtin_amdgcn_exp2f(g[1]));
    float tg = fmaf(2.0f, __builtin_amdgcn_rcpf(1.0f + __builtin_amdgcn_exp2f(g[2])), -1.0f);
    float so = __builtin_amdgcn_rcpf(1.0f + __builtin_amdgcn_exp2f(g[3]));
    float cc = sf * c + si * tg;
    c = cc;
    float tc = fmaf(2.0f, __builtin_amdgcn_rcpf(1.0f +
                    __builtin_amdgcn_exp2f(-2.0f * LOG2E * cc)), -1.0f);
    float hh = so * tc;
    if (real) BQ[posQ] = h_bits((_Float16)hh);
}

__global__ __launch_bounds__(BLK, 2) void lstm_hyb(
    const float* __restrict__ seq,
    const float* __restrict__ Wih_e, const float* __restrict__ Whh_e,
    const float* __restrict__ bih_e, const float* __restrict__ bhh_e,
    const float* __restrict__ Wih_d, const float* __restrict__ Whh_d,
    const float* __restrict__ bih_d, const float* __restrict__ bhh_d,
    const float* __restrict__ Wl, const float* __restrict__ bl,
    float* __restrict__ out)
{
    __shared__ half8 Bsh8[256];             // 2 buffers x 128 chunks (2KB each)
    __shared__ float xs[ROWS * 97];         // 16 steps x 6 feats per row
    __shared__ float Wls[NF * HH];
    __shared__ float bls[NF];

    unsigned short* Bu = (unsigned short*)Bsh8;   // buffer b at ushort ofs b*1024

    const int tid  = threadIdx.x;
    const int w    = tid >> 6;              // 2 waves per block
    const int lane = tid & 63;
    const int q    = lane >> 4;
    const int l15  = lane & 15;
    const int b0   = blockIdx.x * ROWS;
    const int base = w ? 7 : 0;             // wave0: tiles 0..6, wave1: 7..12
    const int nt   = w ? 6 : 7;

    // ---- one-time init ----
    for (int i = tid; i < 256; i += BLK) Bsh8[i] = (half8)(_Float16)0.0f;
    for (int i = tid; i < NF * HH; i += BLK) Wls[i] = Wl[i];
    if (tid < NF) bls[tid] = bl[tid];
    for (int idx = tid; idx < ROWS * 96; idx += BLK) {
        int row = idx / 96, cc = idx - row * 96;
        xs[row * 97 + cc] = seq[(size_t)(b0 + row) * SEQ_STRIDE + cc];
    }
    __syncthreads();
    // bias lane k=56 = 1.0 in BOTH buffers (never overwritten: x k<6, h k 6..55)
    if (tid < 16) {
        Bu[(112 + tid) * 8]        = h_bits((_Float16)1.0f);
        Bu[1024 + (112 + tid) * 8] = h_bits((_Float16)1.0f);
    }
    // x_0 into buf0 (h-slots zero = h0)
    if (tid < 96) {
        int row = tid & 15, n = tid >> 4;
        Bu[row * 8 + n] = h_bits((_Float16)xs[row * 97 + n]);
    }
    __syncthreads();

    // ---- per-tile A fragments (encoder) + constants ----
    half8 a0[NTM], a1[NTM];
    float cst[NTM];
    int   hpos[NTM];
    bool  realu[NTM];
    #pragma unroll
    for (int i = 0; i < NTM; ++i) {
        cst[i] = 0.0f;
        if (i < nt) {
            int tile = base + i;
            int g2 = tile * 16 + l15, u = g2 >> 2, gt = g2 & 3;
            bool v = (u < HH);
            int orow = gt * HH + u;
            float sc = (gt == 2) ? -2.0f * LOG2E : -LOG2E;
            a0[i] = mk8(Wih_e, Whh_e, bih_e, bhh_e, v, orow, sc, q * 8);
            a1[i] = mk8(Wih_e, Whh_e, bih_e, bhh_e, v, orow, sc, 32 + q * 8);
            int uu = tile * 4 + q, k = NF + uu;
            hpos[i] = (((k >> 5) * 64) + ((k >> 3) & 3) * 16 + l15) * 8 + (k & 7);
            realu[i] = (uu < HH);
        }
    }

    // ==== encoder: 12 chunks of 16 + tail 8; 1 barrier/step ====
    for (int t0 = 0; t0 < 192; t0 += 16) {
        #pragma unroll
        for (int k = 0; k < 16; ++k) {
            const int P8 = (k & 1) * 128;
            unsigned short* BQ = Bu + ((k & 1) ^ 1) * 1024;

            half8 bh0 = Bsh8[P8 + lane];
            half8 bh1 = Bsh8[P8 + 64 + lane];
            f32x4 acc[NTM];
            #pragma unroll
            for (int i = 0; i < NTM; ++i) if (i < nt) {
                acc[i] = (f32x4){0.f, 0.f, 0.f, 0.f};
                acc[i] = __builtin_amdgcn_mfma_f32_16x16x32_f16(a0[i], bh0, acc[i], 0, 0, 0);
            }
            #pragma unroll
            for (int i = 0; i < NTM; ++i) if (i < nt)
                acc[i] = __builtin_amdgcn_mfma_f32_16x16x32_f16(a1[i], bh1, acc[i], 0, 0, 0);

            if (k == 15) {
                __syncthreads();           // prior xs reads complete
                const int tn = t0 + 16;    // refresh xs for steps tn .. tn+15
                for (int idx = tid; idx < ROWS * 96; idx += BLK) {
                    int row = idx / 96, cc = idx - row * 96;
                    float v = 0.0f;
                    if (tn + cc / 6 < SS)
                        v = seq[(size_t)(b0 + row) * SEQ_STRIDE + tn * NF + cc];
                    xs[row * 97 + cc] = v;
                }
                __syncthreads();           // new chunk visible
            }
            // x_{t+1} (compile-time slot) into Q
            if (tid < 96) {
                int row = tid & 15, n = tid >> 4;
                BQ[row * 8 + n] =
                    h_bits((_Float16)xs[row * 97 + ((k + 1) & 15) * NF + n]);
            }
            #pragma unroll
            for (int i = 0; i < NTM; ++i) if (i < nt)
                cell_upd(acc[i], cst[i], realu[i], hpos[i], BQ);
            __syncthreads();               // Q complete for next step
        }
    }

    // encoder tail: t = 192..199 (xs slots 0..7)
    #pragma unroll
    for (int k = 0; k < 8; ++k) {
        const int P8 = (k & 1) * 128;
        unsigned short* BQ = Bu + ((k & 1) ^ 1) * 1024;

        half8 bh0 = Bsh8[P8 + lane];
        half8 bh1 = Bsh8[P8 + 64 + lane];
        f32x4 acc[NTM];
        #pragma unroll
        for (int i = 0; i < NTM; ++i) if (i < nt) {
            acc[i] = (f32x4){0.f, 0.f, 0.f, 0.f};
            acc[i] = __builtin_amdgcn_mfma_f32_16x16x32_f16(a0[i], bh0, acc[i], 0, 0, 0);
        }
        #pragma unroll
        for (int i = 0; i < NTM; ++i) if (i < nt)
            acc[i] = __builtin_amdgcn_mfma_f32_16x16x32_f16(a1[i], bh1, acc[i], 0, 0, 0);

        const int slot = (k < 7) ? (k + 1) : 7;   // t=199 writes dec_in = x_199
        if (tid < 96) {
            int row = tid & 15, n = tid >> 4;
            BQ[row * 8 + n] = h_bits((_Float16)xs[row * 97 + slot * NF + n]);
        }
        #pragma unroll
        for (int i = 0; i < NTM; ++i) if (i < nt)
            cell_upd(acc[i], cst[i], realu[i], hpos[i], BQ);
        __syncthreads();
    }

    // ==== switch to decoder weights (registers only) ====
    #pragma unroll
    for (int i = 0; i < NTM; ++i) if (i < nt) {
        int tile = base + i;
        int g2 = tile * 16 + l15, u = g2 >> 2, gt = g2 & 3;
        bool v = (u < HH);
        int orow = gt * HH + u;
        float sc = (gt == 2) ? -2.0f * LOG2E : -LOG2E;
        a0[i] = mk8(Wih_d, Whh_d, bih_d, bhh_d, v, orow, sc, q * 8);
        a1[i] = mk8(Wih_d, Whh_d, bih_d, bhh_d, v, orow, sc, 32 + q * 8);
    }

    // ==== decoder: 5 steps (t=200+d; parity d&1) ====
    #pragma unroll
    for (int d = 0; d < TT; ++d) {
        const int P8 = (d & 1) * 128;
        unsigned short* BQ = Bu + ((d & 1) ^ 1) * 1024;

        half8 bh0 = Bsh8[P8 + lane];
        half8 bh1 = Bsh8[P8 + 64 + lane];
        f32x4 acc[NTM];
        #pragma unroll
        for (int i = 0; i < NTM; ++i) if (i < nt) {
            acc[i] = (f32x4){0.f, 0.f, 0.f, 0.f};
            acc[i] = __builtin_amdgcn_mfma_f32_16x16x32_f16(a0[i], bh0, acc[i], 0, 0, 0);
        }
        #pragma unroll
        for (int i = 0; i < NTM; ++i) if (i < nt)
            acc[i] = __builtin_amdgcn_mfma_f32_16x16x32_f16(a1[i], bh1, acc[i], 0, 0, 0);
        #pragma unroll
        for (int i = 0; i < NTM; ++i) if (i < nt)
            cell_upd(acc[i], cst[i], realu[i], hpos[i], BQ);
        __syncthreads();                   // h_t visible in Q

        if (tid < 96) {
            int row = tid & 15, n = tid >> 4;
            float a = bls[n];
            #pragma unroll
            for (int u2 = 0; u2 < HH; ++u2) {
                int kk = NF + u2;
                int pos = ((kk >> 5) * 64 + ((kk >> 3) & 3) * 16 + row) * 8 + (kk & 7);
                a = fmaf(Wls[n * HH + u2], h_f(BQ[pos]), a);
            }
            out[(size_t)(b0 + row) * (TT * NF) + d * NF + n] = a;
            BQ[row * 8 + n] = h_bits((_Float16)a);   // feed back as next x
        }
        __syncthreads();                   // Q (incl. x) complete
    }
}

extern "C" void kernel_launch(void* const* d_in, const int* in_sizes, int n_in,
                              void* d_out, int out_size, void* d_ws, size_t ws_size,
                              hipStream_t stream)
{
    const float* seq   = (const float*)d_in[0];
    const float* Wih_e = (const float*)d_in[1];
    const float* Whh_e = (const float*)d_in[2];
    const float* bih_e = (const float*)d_in[3];
    const float* bhh_e = (const float*)d_in[4];
    const float* Wih_d = (const float*)d_in[5];
    const float* Whh_d = (const float*)d_in[6];
    const float* bih_d = (const float*)d_in[7];
    const float* bhh_d = (const float*)d_in[8];
    const float* Wl    = (const float*)d_in[9];
    const float* bl    = (const float*)d_in[10];
    float* out = (float*)d_out;

    dim3 grid(BB / ROWS);   // 1024 blocks x 2 waves -> 8 waves/CU = 2/SIMD
    dim3 block(BLK);
    lstm_hyb<<<grid, block, 0, stream>>>(seq, Wih_e, Whh_e, bih_e, bhh_e,
                                         Wih_d, Whh_d, bih_d, bhh_d,
                                         Wl, bl, out);
}